// Round 23
// baseline (375.767 us; speedup 1.0000x reference)
//
#include <hip/hip_runtime.h>
#include <hip/hip_bf16.h>

typedef __attribute__((ext_vector_type(8))) _Float16 f16x8;
typedef __attribute__((ext_vector_type(4))) float f32x4;

#define NROWS 262144
#define MBLK  32
#define NBLKS (NROWS / MBLK)   /* 8192 */

// ---------------------------------------------------------------------------
// Weight prep: SINGLE fp16 B-fragment buffer, keyed (w,g,kk):
//   elem (w,g,kk,lane,j) = Wbig[g][n = w*16 + (lane&15)]
//                                [k = kk*32 + (lane>>4)*8 + j]
//   at offset ((w*32 + g*8 + kk)*64 + lane)*8 + j.
// ---------------------------------------------------------------------------
__global__ void prep_weights(
    const float* __restrict__ Wi, const float* __restrict__ Ui,
    const float* __restrict__ Wf, const float* __restrict__ Uf,
    const float* __restrict__ Wo, const float* __restrict__ Uo,
    const float* __restrict__ Wz, const float* __restrict__ Uz,
    ushort* __restrict__ wh)
{
    int idx = blockIdx.x * 256 + threadIdx.x;   // 0..131071
    int j    = idx & 7;
    int lane = (idx >> 3) & 63;
    int kk   = (idx >> 9) & 7;
    int g    = (idx >> 12) & 3;
    int w    = (idx >> 14) & 7;
    int n = w * 16 + (lane & 15);
    int k = kk * 32 + (lane >> 4) * 8 + j;
    const float* W; const float* U;
    if (g == 0)      { W = Wi; U = Ui; }
    else if (g == 1) { W = Wf; U = Uf; }
    else if (g == 2) { W = Wo; U = Uo; }
    else             { W = Wz; U = Uz; }
    float v = (k < 128) ? W[n * 128 + k] : U[n * 128 + (k - 128)];
    _Float16 hh = (_Float16)v;                  // RNE (weights stay RNE)
    wh[idx] = __builtin_bit_cast(ushort, hh);
}

// ---------------------------------------------------------------------------
// Main fused kernel. 8192 blocks; 512 thr = 8 waves; MBLK=32 rows.
// R22 chassis (single-term fp16 RTZ-A/RNE-B, col-partition, wide f32x4
// epilogue via padded pre[16][516], per-chunk c/n loads in the barrier
// window) with launch_bounds(512,8): unified cap 64 (acc 32 AGPR + ~32
// arch) -> 4 blocks/CU, 8 waves/SIMD. LDS 4x33KB = 132 <= 160 OK.
// Stage loop unroll(1) keeps live loads to one iteration at the tight cap.
// Falsifier: WRITE_SIZE > 450 MB = spilled -> revert to (512,6).
// ---------------------------------------------------------------------------
__global__ __launch_bounds__(512, 8) void slstm_main(
    const float* __restrict__ x,     const float* __restrict__ hprev,
    const float* __restrict__ cprev, const float* __restrict__ nprev,
    const float* __restrict__ bi,    const float* __restrict__ bfg,
    const float* __restrict__ bo,    const float* __restrict__ bz,
    const ushort* __restrict__ wh,
    float* __restrict__ out)
{
    __shared__ float pre[16 * 516];   // 33 KB; first 16 KB doubles as A-tile
    char* AB = reinterpret_cast<char*>(pre);

    const int tid  = threadIdx.x;
    const int row0 = blockIdx.x * MBLK;

    // ---- stage A: fp32 loads -> packed RTZ fp16, swizzled LDS ----
    #pragma unroll 1
    for (int i = 0; i < 2; ++i) {
        int f4  = tid + i * 512;          // 0..1023
        int row = f4 >> 5;                // 0..31
        int c4  = f4 & 31;
        f32x4 vx = reinterpret_cast<const f32x4*>(x)[(size_t)(row0 + row) * 32 + c4];
        f32x4 vh = reinterpret_cast<const f32x4*>(hprev)[(size_t)(row0 + row) * 32 + c4];
        #pragma unroll
        for (int half = 0; half < 2; ++half) {
            f32x4 v = half ? vh : vx;
            int kbase = half * 128 + 4 * c4;
            int q   = kbase >> 3;
            int sub = (kbase & 7) * 2;
            int byt = row * 512 + ((q ^ (row & 7)) << 4) + sub;
            auto p0 = __builtin_amdgcn_cvt_pkrtz(v[0], v[1]);
            auto p1 = __builtin_amdgcn_cvt_pkrtz(v[2], v[3]);
            uint2 hp;
            hp.x = __builtin_bit_cast(uint, p0);
            hp.y = __builtin_bit_cast(uint, p1);
            *reinterpret_cast<uint2*>(AB + byt) = hp;
        }
    }
    __syncthreads();   // bar 1

    const int w    = tid >> 6;         // wave id = column group
    const int lane = tid & 63;
    const int l15  = lane & 15;
    const int lg   = lane >> 4;

    // wave-constant B base (this wave's 16-col slice, all gates)
    const ushort* whW = wh + (size_t)(w * 32) * 512 + lane * 8;

    // ---- K-loop: single-term fp16 MFMA; acc[gate][mi] ----
    f32x4 acc[4][2] = {};

    #pragma unroll
    for (int kk = 0; kk < 8; ++kk) {
        f16x8 ah[2];
        #pragma unroll
        for (int mi = 0; mi < 2; ++mi) {
            int row = mi * 16 + l15;
            int q   = kk * 4 + lg;
            int byt = row * 512 + ((q ^ (row & 7)) << 4);
            ah[mi] = *reinterpret_cast<const f16x8*>(AB + byt);
        }
        #pragma unroll
        for (int g = 0; g < 4; ++g) {
            f16x8 b = *reinterpret_cast<const f16x8*>(whW + (g * 8 + kk) * 512);
            #pragma unroll
            for (int mi = 0; mi < 2; ++mi)
                acc[g][mi] = __builtin_amdgcn_mfma_f32_16x16x32_f16(ah[mi], b, acc[g][mi], 0, 0, 0);
        }
    }

    // ---- wide epilogue: 2 chunks of 16 rows via pre[16][516] ----
    const size_t OUTS = (size_t)NROWS * 128;
    const int rloc = tid >> 5;            // 0..15  (row within chunk)
    const int c0   = (tid & 31) * 4;      // 0..124 (4 consecutive cols)
    const f32x4 bi4 = *reinterpret_cast<const f32x4*>(bi  + c0);
    const f32x4 bf4 = *reinterpret_cast<const f32x4*>(bfg + c0);
    const f32x4 bo4 = *reinterpret_cast<const f32x4*>(bo  + c0);
    const f32x4 bz4 = *reinterpret_cast<const f32x4*>(bz  + c0);

    #pragma unroll
    for (int ck = 0; ck < 2; ++ck) {
        __syncthreads();   // ck=0: K-loop A reads done; ck=1: chunk0 reads done
        #pragma unroll
        for (int g = 0; g < 4; ++g)
            #pragma unroll
            for (int r = 0; r < 4; ++r)
                pre[(lg * 4 + r) * 516 + g * 128 + w * 16 + l15] = acc[g][ck][r];

        // issue c/n loads NOW: latency hides under the barrier + pre reads;
        // lifetime does not cross the K-loop (no spill)
        const size_t gidx = (size_t)(row0 + ck * 16 + rloc) * 128 + c0;
        f32x4 cp4 = *reinterpret_cast<const f32x4*>(cprev + gidx);
        f32x4 np4 = *reinterpret_cast<const f32x4*>(nprev + gidx);
        __syncthreads();

        f32x4 p_i = *reinterpret_cast<const f32x4*>(&pre[rloc * 516 +       c0]);
        f32x4 p_f = *reinterpret_cast<const f32x4*>(&pre[rloc * 516 + 128 + c0]);
        f32x4 p_o = *reinterpret_cast<const f32x4*>(&pre[rloc * 516 + 256 + c0]);
        f32x4 p_z = *reinterpret_cast<const f32x4*>(&pre[rloc * 516 + 384 + c0]);

        f32x4 hv, cv, nv;
        #pragma unroll
        for (int e = 0; e < 4; ++e) {
            float pit = p_i[e] + bi4[e];
            float pft = p_f[e] + bf4[e];
            float pot = p_o[e] + bo4[e];
            float pzt = p_z[e] + bz4[e];
            float m   = fmaxf(pft, pit);
            float i_t = __expf(pit - m);
            float f_t = __builtin_amdgcn_rcpf(1.0f + __expf(-pft)) + __expf(pft - m);
            float o_t = __builtin_amdgcn_rcpf(1.0f + __expf(-pot));
            float zc  = fminf(fmaxf(pzt, -15.0f), 15.0f);
            float e2  = __expf(2.0f * zc);
            float z_t = (e2 - 1.0f) * __builtin_amdgcn_rcpf(e2 + 1.0f);
            float c_t = f_t * cp4[e] + i_t * z_t;
            float n_t = f_t * np4[e] + i_t;
            float h_t = o_t * c_t * __builtin_amdgcn_rcpf(n_t + 1e-8f);
            hv[e] = h_t; cv[e] = c_t; nv[e] = n_t;
        }
        *reinterpret_cast<f32x4*>(out + gidx)            = hv;
        *reinterpret_cast<f32x4*>(out + OUTS + gidx)     = cv;
        *reinterpret_cast<f32x4*>(out + 2 * OUTS + gidx) = nv;
    }
}

extern "C" void kernel_launch(void* const* d_in, const int* in_sizes, int n_in,
                              void* d_out, int out_size, void* d_ws, size_t ws_size,
                              hipStream_t stream) {
    const float* x  = (const float*)d_in[0];
    const float* h  = (const float*)d_in[1];
    const float* cp = (const float*)d_in[2];
    const float* np = (const float*)d_in[3];
    const float* Wi = (const float*)d_in[4];
    const float* Ui = (const float*)d_in[5];
    const float* Wf = (const float*)d_in[6];
    const float* Uf = (const float*)d_in[7];
    const float* Wo = (const float*)d_in[8];
    const float* Uo = (const float*)d_in[9];
    const float* Wz = (const float*)d_in[10];
    const float* Uz = (const float*)d_in[11];
    const float* bi = (const float*)d_in[12];
    const float* bf = (const float*)d_in[13];
    const float* bo = (const float*)d_in[14];
    const float* bz = (const float*)d_in[15];

    ushort* wh = (ushort*)d_ws;                   // 256 KB fp16 fragments

    prep_weights<<<512, 256, 0, stream>>>(Wi, Ui, Wf, Uf, Wo, Uo, Wz, Uz, wh);
    slstm_main<<<NBLKS, 512, 0, stream>>>(x, h, cp, np, bi, bf, bo, bz, wh,
                                          (float*)d_out);
}

// Round 24
// 226.180 us; speedup vs baseline: 1.6614x; 1.6614x over previous
//
#include <hip/hip_runtime.h>
#include <hip/hip_bf16.h>

typedef __attribute__((ext_vector_type(8))) _Float16 f16x8;
typedef __attribute__((ext_vector_type(4))) float f32x4;

#define NROWS 262144
#define MBLK  32
#define NBLKS (NROWS / MBLK)   /* 8192 */

// ---------------------------------------------------------------------------
// Weight prep: SINGLE fp16 B-fragment buffer, keyed (w,g,kk):
//   elem (w,g,kk,lane,j) = Wbig[g][n = w*16 + (lane&15)]
//                                [k = kk*32 + (lane>>4)*8 + j]
//   at offset ((w*32 + g*8 + kk)*64 + lane)*8 + j.
// ---------------------------------------------------------------------------
__global__ void prep_weights(
    const float* __restrict__ Wi, const float* __restrict__ Ui,
    const float* __restrict__ Wf, const float* __restrict__ Uf,
    const float* __restrict__ Wo, const float* __restrict__ Uo,
    const float* __restrict__ Wz, const float* __restrict__ Uz,
    ushort* __restrict__ wh)
{
    int idx = blockIdx.x * 256 + threadIdx.x;   // 0..131071
    int j    = idx & 7;
    int lane = (idx >> 3) & 63;
    int kk   = (idx >> 9) & 7;
    int g    = (idx >> 12) & 3;
    int w    = (idx >> 14) & 7;
    int n = w * 16 + (lane & 15);
    int k = kk * 32 + (lane >> 4) * 8 + j;
    const float* W; const float* U;
    if (g == 0)      { W = Wi; U = Ui; }
    else if (g == 1) { W = Wf; U = Uf; }
    else if (g == 2) { W = Wo; U = Uo; }
    else             { W = Wz; U = Uz; }
    float v = (k < 128) ? W[n * 128 + k] : U[n * 128 + (k - 128)];
    _Float16 hh = (_Float16)v;                  // RNE (weights stay RNE)
    wh[idx] = __builtin_bit_cast(ushort, hh);
}

// ---------------------------------------------------------------------------
// Main fused kernel. 8192 blocks; 512 thr = 8 waves; MBLK=32 rows.
// R22 configuration (best measured: 227 us):
//  - single-term fp16 (RTZ A via cvt_pkrtz, RNE B), 16 MFMA/kk-iter total
//  - wave w owns cols [16w,16w+16) x ALL 4 gates (acc[4][2] = 32 AGPRs)
//  - launch_bounds(512,6) -> 3 blocks/CU, no spills (VGPR 40)
//  - wide f32x4 epilogue via padded pre[16][516] (2 chunks of 16 rows)
//  - per-chunk c/n loads issued in the barrier window (hidden, no spill)
// ---------------------------------------------------------------------------
__global__ __launch_bounds__(512, 6) void slstm_main(
    const float* __restrict__ x,     const float* __restrict__ hprev,
    const float* __restrict__ cprev, const float* __restrict__ nprev,
    const float* __restrict__ bi,    const float* __restrict__ bfg,
    const float* __restrict__ bo,    const float* __restrict__ bz,
    const ushort* __restrict__ wh,
    float* __restrict__ out)
{
    __shared__ float pre[16 * 516];   // 33 KB; first 16 KB doubles as A-tile
    char* AB = reinterpret_cast<char*>(pre);

    const int tid  = threadIdx.x;
    const int row0 = blockIdx.x * MBLK;

    // ---- stage A: fp32 loads -> packed RTZ fp16, swizzled LDS ----
    #pragma unroll
    for (int i = 0; i < 2; ++i) {
        int f4  = tid + i * 512;          // 0..1023
        int row = f4 >> 5;                // 0..31
        int c4  = f4 & 31;
        f32x4 vx = reinterpret_cast<const f32x4*>(x)[(size_t)(row0 + row) * 32 + c4];
        f32x4 vh = reinterpret_cast<const f32x4*>(hprev)[(size_t)(row0 + row) * 32 + c4];
        #pragma unroll
        for (int half = 0; half < 2; ++half) {
            f32x4 v = half ? vh : vx;
            int kbase = half * 128 + 4 * c4;
            int q   = kbase >> 3;
            int sub = (kbase & 7) * 2;
            int byt = row * 512 + ((q ^ (row & 7)) << 4) + sub;
            auto p0 = __builtin_amdgcn_cvt_pkrtz(v[0], v[1]);
            auto p1 = __builtin_amdgcn_cvt_pkrtz(v[2], v[3]);
            uint2 hp;
            hp.x = __builtin_bit_cast(uint, p0);
            hp.y = __builtin_bit_cast(uint, p1);
            *reinterpret_cast<uint2*>(AB + byt) = hp;
        }
    }
    __syncthreads();   // bar 1

    const int w    = tid >> 6;         // wave id = column group
    const int lane = tid & 63;
    const int l15  = lane & 15;
    const int lg   = lane >> 4;

    // wave-constant B base (this wave's 16-col slice, all gates)
    const ushort* whW = wh + (size_t)(w * 32) * 512 + lane * 8;

    // ---- K-loop: single-term fp16 MFMA; acc[gate][mi] ----
    f32x4 acc[4][2] = {};

    #pragma unroll
    for (int kk = 0; kk < 8; ++kk) {
        f16x8 ah[2];
        #pragma unroll
        for (int mi = 0; mi < 2; ++mi) {
            int row = mi * 16 + l15;
            int q   = kk * 4 + lg;
            int byt = row * 512 + ((q ^ (row & 7)) << 4);
            ah[mi] = *reinterpret_cast<const f16x8*>(AB + byt);
        }
        #pragma unroll
        for (int g = 0; g < 4; ++g) {
            f16x8 b = *reinterpret_cast<const f16x8*>(whW + (g * 8 + kk) * 512);
            #pragma unroll
            for (int mi = 0; mi < 2; ++mi)
                acc[g][mi] = __builtin_amdgcn_mfma_f32_16x16x32_f16(ah[mi], b, acc[g][mi], 0, 0, 0);
        }
    }

    // ---- wide epilogue: 2 chunks of 16 rows via pre[16][516] ----
    const size_t OUTS = (size_t)NROWS * 128;
    const int rloc = tid >> 5;            // 0..15  (row within chunk)
    const int c0   = (tid & 31) * 4;      // 0..124 (4 consecutive cols)
    const f32x4 bi4 = *reinterpret_cast<const f32x4*>(bi  + c0);
    const f32x4 bf4 = *reinterpret_cast<const f32x4*>(bfg + c0);
    const f32x4 bo4 = *reinterpret_cast<const f32x4*>(bo  + c0);
    const f32x4 bz4 = *reinterpret_cast<const f32x4*>(bz  + c0);

    #pragma unroll
    for (int ck = 0; ck < 2; ++ck) {
        __syncthreads();   // ck=0: K-loop A reads done; ck=1: chunk0 reads done
        #pragma unroll
        for (int g = 0; g < 4; ++g)
            #pragma unroll
            for (int r = 0; r < 4; ++r)
                pre[(lg * 4 + r) * 516 + g * 128 + w * 16 + l15] = acc[g][ck][r];

        // issue c/n loads NOW: latency hides under the barrier + pre reads;
        // lifetime does not cross the K-loop (no spill)
        const size_t gidx = (size_t)(row0 + ck * 16 + rloc) * 128 + c0;
        f32x4 cp4 = *reinterpret_cast<const f32x4*>(cprev + gidx);
        f32x4 np4 = *reinterpret_cast<const f32x4*>(nprev + gidx);
        __syncthreads();

        f32x4 p_i = *reinterpret_cast<const f32x4*>(&pre[rloc * 516 +       c0]);
        f32x4 p_f = *reinterpret_cast<const f32x4*>(&pre[rloc * 516 + 128 + c0]);
        f32x4 p_o = *reinterpret_cast<const f32x4*>(&pre[rloc * 516 + 256 + c0]);
        f32x4 p_z = *reinterpret_cast<const f32x4*>(&pre[rloc * 516 + 384 + c0]);

        f32x4 hv, cv, nv;
        #pragma unroll
        for (int e = 0; e < 4; ++e) {
            float pit = p_i[e] + bi4[e];
            float pft = p_f[e] + bf4[e];
            float pot = p_o[e] + bo4[e];
            float pzt = p_z[e] + bz4[e];
            float m   = fmaxf(pft, pit);
            float i_t = __expf(pit - m);
            float f_t = __builtin_amdgcn_rcpf(1.0f + __expf(-pft)) + __expf(pft - m);
            float o_t = __builtin_amdgcn_rcpf(1.0f + __expf(-pot));
            float zc  = fminf(fmaxf(pzt, -15.0f), 15.0f);
            float e2  = __expf(2.0f * zc);
            float z_t = (e2 - 1.0f) * __builtin_amdgcn_rcpf(e2 + 1.0f);
            float c_t = f_t * cp4[e] + i_t * z_t;
            float n_t = f_t * np4[e] + i_t;
            float h_t = o_t * c_t * __builtin_amdgcn_rcpf(n_t + 1e-8f);
            hv[e] = h_t; cv[e] = c_t; nv[e] = n_t;
        }
        *reinterpret_cast<f32x4*>(out + gidx)            = hv;
        *reinterpret_cast<f32x4*>(out + OUTS + gidx)     = cv;
        *reinterpret_cast<f32x4*>(out + 2 * OUTS + gidx) = nv;
    }
}

extern "C" void kernel_launch(void* const* d_in, const int* in_sizes, int n_in,
                              void* d_out, int out_size, void* d_ws, size_t ws_size,
                              hipStream_t stream) {
    const float* x  = (const float*)d_in[0];
    const float* h  = (const float*)d_in[1];
    const float* cp = (const float*)d_in[2];
    const float* np = (const float*)d_in[3];
    const float* Wi = (const float*)d_in[4];
    const float* Ui = (const float*)d_in[5];
    const float* Wf = (const float*)d_in[6];
    const float* Uf = (const float*)d_in[7];
    const float* Wo = (const float*)d_in[8];
    const float* Uo = (const float*)d_in[9];
    const float* Wz = (const float*)d_in[10];
    const float* Uz = (const float*)d_in[11];
    const float* bi = (const float*)d_in[12];
    const float* bf = (const float*)d_in[13];
    const float* bo = (const float*)d_in[14];
    const float* bz = (const float*)d_in[15];

    ushort* wh = (ushort*)d_ws;                   // 256 KB fp16 fragments

    prep_weights<<<512, 256, 0, stream>>>(Wi, Ui, Wf, Uf, Wo, Uo, Wz, Uz, wh);
    slstm_main<<<NBLKS, 512, 0, stream>>>(x, h, cp, np, bi, bf, bo, bz, wh,
                                          (float*)d_out);
}